// Round 1
// baseline (5877.577 us; speedup 1.0000x reference)
//
#include <hip/hip_runtime.h>

// ---------------------------------------------------------------------------
// FullModelSnowflake: KNN -> GCN x2 -> enc -> 4x transformer (geom bias attn)
// -> decoder -> 3x local-refine stages.  B=2, N=1024, D=128, H=8, DK=16.
// All fp32.  Round 0: correctness-first, straightforward kernels.
// ---------------------------------------------------------------------------

#define B_ 2
#define N_ 1024
#define D_ 128
#define H_ 8
#define DK_ 16
#define L_ 4
#define KG_ 16
#define KLOC_ 8
#define COARSE_ 512

static __device__ __forceinline__ float wave_sum(float v) {
    #pragma unroll
    for (int off = 32; off > 0; off >>= 1) v += __shfl_xor(v, off);
    return v;
}
static __device__ __forceinline__ float wave_max(float v) {
    #pragma unroll
    for (int off = 32; off > 0; off >>= 1) v = fmaxf(v, __shfl_xor(v, off));
    return v;
}

// ---------------- KNN self graph (k=16, exclude self) ----------------------
// grid: B blocks x 1024 threads.  coords + r^2 staged in LDS.
__global__ void knn_self_kernel(const float* __restrict__ coords,
                                int* __restrict__ knn) {
    int b = blockIdx.x;
    int n = threadIdx.x;
    __shared__ float cx[N_], cy[N_], cz[N_], r2[N_];
    const float* cb = coords + (size_t)b * N_ * 3;
    float x = cb[n * 3], y = cb[n * 3 + 1], z = cb[n * 3 + 2];
    cx[n] = x; cy[n] = y; cz[n] = z;
    r2[n] = x * x + y * y + z * z;
    __syncthreads();
    float qx = x, qy = y, qz = z, q2 = r2[n];
    float bd[KG_]; int bi[KG_];
    #pragma unroll
    for (int j = 0; j < KG_; ++j) { bd[j] = 3e38f; bi[j] = 0; }
    for (int m = 0; m < N_; ++m) {
        if (m == n) continue;
        float dot = qx * cx[m] + qy * cy[m] + qz * cz[m];
        float d = (q2 - 2.0f * dot) + r2[m];
        if (d < bd[KG_ - 1]) {
            int j = KG_ - 1;
            while (j > 0 && bd[j - 1] > d) { bd[j] = bd[j - 1]; bi[j] = bi[j - 1]; --j; }
            bd[j] = d; bi[j] = m;
        }
    }
    int* o = knn + ((size_t)b * N_ + n) * KG_;
    #pragma unroll
    for (int j = 0; j < KG_; ++j) o[j] = bi[j];
}

// ---------------- Gram matrix G[b,n,m] = coords[b,n] . coords[b,m] ---------
__global__ void gram_kernel(const float* __restrict__ coords,
                            float* __restrict__ G) {
    int i = blockIdx.x * blockDim.x + threadIdx.x;
    if (i >= B_ * N_ * N_) return;
    int m = i & (N_ - 1);
    int n = (i >> 10) & (N_ - 1);
    int b = i >> 20;
    const float* a = coords + ((size_t)b * N_ + n) * 3;
    const float* c = coords + ((size_t)b * N_ + m) * 3;
    G[i] = a[0] * c[0] + a[1] * c[1] + a[2] * c[2];
}

// ---------------- GCN aggregation: (x + sum_nb) / (k+1) --------------------
__global__ void gcn_agg_kernel(const float* __restrict__ x,
                               const int* __restrict__ knn,
                               float* __restrict__ agg, int C) {
    int i = blockIdx.x * blockDim.x + threadIdx.x;
    if (i >= B_ * N_ * C) return;
    int c = i % C;
    int n = (i / C) % N_;
    int b = i / (C * N_);
    const int* id = knn + ((size_t)b * N_ + n) * KG_;
    float s = x[((size_t)b * N_ + n) * C + c];
    #pragma unroll
    for (int j = 0; j < KG_; ++j) s += x[((size_t)b * N_ + id[j]) * C + c];
    agg[i] = s * (1.0f / (KG_ + 1));
}

// ---------------- generic linear: Y = act(X @ W + b) -----------------------
// X:[rows,Cin] W:[Cin,Cout] b:[Cout]
template <bool RELU>
__global__ void linear_kernel(const float* __restrict__ X,
                              const float* __restrict__ W,
                              const float* __restrict__ bias,
                              float* __restrict__ Y,
                              int rows, int Cin, int Cout) {
    int idx = blockIdx.x * blockDim.x + threadIdx.x;
    if (idx >= rows * Cout) return;
    int r = idx / Cout, o = idx - r * Cout;
    const float* x = X + (size_t)r * Cin;
    float acc = bias[o];
    for (int c = 0; c < Cin; ++c) acc += x[c] * W[(size_t)c * Cout + o];
    if (RELU) acc = fmaxf(acc, 0.f);
    Y[idx] = acc;
}

// ---------------- fused attention: one wave per (b,h,n) --------------------
// q,k,v: [B,N,128] laid out h*16+d.  out same layout.
__global__ void attn_kernel(const float* __restrict__ q,
                            const float* __restrict__ k,
                            const float* __restrict__ v,
                            const float* __restrict__ G,
                            const float* __restrict__ alphap, int layer,
                            float* __restrict__ outp) {
    int wid = threadIdx.x >> 6;
    int lane = threadIdx.x & 63;
    int gw = blockIdx.x * 4 + wid;       // (b*H + h)*N + n
    int n = gw & (N_ - 1);
    int h = (gw >> 10) & (H_ - 1);
    int b = gw >> 13;
    float alpha = alphap[layer];
    const float* qp = q + ((size_t)(b * N_ + n) * D_ + h * DK_);
    float qv[DK_];
    #pragma unroll
    for (int d = 0; d < DK_; ++d) qv[d] = qp[d];
    const float* Gp = G + ((size_t)b * N_ + n) * N_;
    float s[16];
    float mx = -3e38f;
    #pragma unroll
    for (int j = 0; j < 16; ++j) {
        int m = j * 64 + lane;
        const float* kp = k + ((size_t)(b * N_ + m) * D_ + h * DK_);
        float dot = 0.f;
        #pragma unroll
        for (int d = 0; d < DK_; ++d) dot += qv[d] * kp[d];
        s[j] = dot * 0.25f + alpha * Gp[m];
        mx = fmaxf(mx, s[j]);
    }
    mx = wave_max(mx);
    float sum = 0.f;
    #pragma unroll
    for (int j = 0; j < 16; ++j) { s[j] = expf(s[j] - mx); sum += s[j]; }
    sum = wave_sum(sum);
    float acc[DK_];
    #pragma unroll
    for (int d = 0; d < DK_; ++d) acc[d] = 0.f;
    #pragma unroll
    for (int j = 0; j < 16; ++j) {
        int m = j * 64 + lane;
        const float* vp = v + ((size_t)(b * N_ + m) * D_ + h * DK_);
        #pragma unroll
        for (int d = 0; d < DK_; ++d) acc[d] += s[j] * vp[d];
    }
    float inv = 1.0f / sum;
    float* op = outp + ((size_t)(b * N_ + n) * D_ + h * DK_);
    #pragma unroll
    for (int d = 0; d < DK_; ++d) {
        float a = wave_sum(acc[d]);
        if (lane == d) op[d] = a * inv;
    }
}

// ---------------- residual add + LayerNorm (row=128), 1 wave/row -----------
__global__ void add_ln_kernel(const float* __restrict__ a,
                              const float* __restrict__ res,
                              const float* __restrict__ g,
                              const float* __restrict__ bt,
                              float* __restrict__ outp) {
    int row = blockIdx.x * 4 + (threadIdx.x >> 6);
    int lane = threadIdx.x & 63;
    const float* ar = a + (size_t)row * D_;
    const float* rr = res + (size_t)row * D_;
    float v0 = ar[lane] + rr[lane];
    float v1 = ar[lane + 64] + rr[lane + 64];
    float mean = wave_sum(v0 + v1) * (1.0f / D_);
    float d0 = v0 - mean, d1 = v1 - mean;
    float var = wave_sum(d0 * d0 + d1 * d1) * (1.0f / D_);
    float rstd = rsqrtf(var + 1e-5f);
    float* orow = outp + (size_t)row * D_;
    orow[lane] = d0 * rstd * g[lane] + bt[lane];
    orow[lane + 64] = d1 * rstd * g[lane + 64] + bt[lane + 64];
}

// ---------------- column mean over N (global feature) ----------------------
__global__ void colmean_kernel(const float* __restrict__ x,
                               float* __restrict__ gc) {
    int b = blockIdx.x, d = threadIdx.x;
    double s = 0.0;
    for (int n = 0; n < N_; ++n) s += (double)x[((size_t)b * N_ + n) * D_ + d];
    gc[b * D_ + d] = (float)(s * (1.0 / N_));
}

// ---------------- local KNN (k=8) mean + build comb=[pred,nm] --------------
// grid: (Nq/256, B) x 256 threads
__global__ void neigh_comb_kernel(const float* __restrict__ part,
                                  const float* __restrict__ pred,
                                  float* __restrict__ comb, int Nq) {
    int b = blockIdx.y;
    int n = blockIdx.x * blockDim.x + threadIdx.x;
    __shared__ float cx[N_], cy[N_], cz[N_], r2[N_];
    const float* pb = part + (size_t)b * N_ * 3;
    for (int i = threadIdx.x; i < N_; i += blockDim.x) {
        float x = pb[i * 3], y = pb[i * 3 + 1], z = pb[i * 3 + 2];
        cx[i] = x; cy[i] = y; cz[i] = z;
        r2[i] = x * x + y * y + z * z;
    }
    __syncthreads();
    if (n >= Nq) return;
    const float* pr = pred + ((size_t)b * Nq + n) * 3;
    float qx = pr[0], qy = pr[1], qz = pr[2];
    float q2 = qx * qx + qy * qy + qz * qz;
    float bd[KLOC_]; int bi[KLOC_];
    #pragma unroll
    for (int j = 0; j < KLOC_; ++j) { bd[j] = 3e38f; bi[j] = 0; }
    for (int m = 0; m < N_; ++m) {
        float dot = qx * cx[m] + qy * cy[m] + qz * cz[m];
        float d = (q2 - 2.0f * dot) + r2[m];
        if (d < bd[KLOC_ - 1]) {
            int j = KLOC_ - 1;
            while (j > 0 && bd[j - 1] > d) { bd[j] = bd[j - 1]; bi[j] = bi[j - 1]; --j; }
            bd[j] = d; bi[j] = m;
        }
    }
    float sx = 0.f, sy = 0.f, sz = 0.f;
    #pragma unroll
    for (int j = 0; j < KLOC_; ++j) { sx += cx[bi[j]]; sy += cy[bi[j]]; sz += cz[bi[j]]; }
    float* o = comb + ((size_t)b * Nq + n) * 6;
    o[0] = qx; o[1] = qy; o[2] = qz;
    o[3] = sx * (1.0f / KLOC_); o[4] = sy * (1.0f / KLOC_); o[5] = sz * (1.0f / KLOC_);
}

// ---------------- ConvT1d(k=2,s=2) on len-1 seq: h[.,o,t]=relu(seed.dw+db) -
// dw flat [128][128][2] -> treat as linear 128 -> 256 with bias db[ot>>1]
__global__ void convt_kernel(const float* __restrict__ seed,
                             const float* __restrict__ dw,
                             const float* __restrict__ db,
                             float* __restrict__ h, int rows) {
    int idx = blockIdx.x * blockDim.x + threadIdx.x;
    if (idx >= rows * 256) return;
    int r = idx >> 8, ot = idx & 255;
    const float* x = seed + (size_t)r * 128;
    float acc = db[ot >> 1];
    for (int c = 0; c < 128; ++c) acc += x[c] * dw[(size_t)c * 256 + ot];
    h[idx] = fmaxf(acc, 0.f);
}

// ---------------- child = pred + (h . cw + cb), interleaved x2 -------------
__global__ void child_kernel(const float* __restrict__ h,
                             const float* __restrict__ cw,
                             const float* __restrict__ cb,
                             const float* __restrict__ pred,
                             float* __restrict__ outp, int Nq) {
    int idx = blockIdx.x * blockDim.x + threadIdx.x;
    if (idx >= B_ * Nq * 6) return;
    int p = idx % 3;
    int t = (idx / 3) & 1;
    int n = (idx / 6) % Nq;
    int b = idx / (6 * Nq);
    const float* hr = h + ((size_t)b * Nq + n) * 256;
    float acc = cb[p];
    for (int o = 0; o < 128; ++o) acc += hr[o * 2 + t] * cw[p * 128 + o];
    outp[idx] = pred[((size_t)b * Nq + n) * 3 + p] + acc;
}

// ---------------------------------------------------------------------------
static inline int cdiv(int a, int b) { return (a + b - 1) / b; }

extern "C" void kernel_launch(void* const* d_in, const int* in_sizes, int n_in,
                              void* d_out, int out_size, void* d_ws, size_t ws_size,
                              hipStream_t stream) {
    (void)in_sizes; (void)n_in; (void)out_size; (void)ws_size;
    const float* coords = (const float*)d_in[0];
    const float* gcn_w0 = (const float*)d_in[1];
    const float* gcn_b0 = (const float*)d_in[2];
    const float* gcn_w1 = (const float*)d_in[3];
    const float* gcn_b1 = (const float*)d_in[4];
    const float* enc_fw = (const float*)d_in[5];
    const float* enc_fb = (const float*)d_in[6];
    const float* t_wq   = (const float*)d_in[7];
    const float* t_bq   = (const float*)d_in[8];
    const float* t_wk   = (const float*)d_in[9];
    const float* t_bk   = (const float*)d_in[10];
    const float* t_wv   = (const float*)d_in[11];
    const float* t_bv   = (const float*)d_in[12];
    const float* t_alpha= (const float*)d_in[13];
    const float* t_f1w  = (const float*)d_in[14];
    const float* t_f1b  = (const float*)d_in[15];
    const float* t_f2w  = (const float*)d_in[16];
    const float* t_f2b  = (const float*)d_in[17];
    const float* t_ln1g = (const float*)d_in[18];
    const float* t_ln1b = (const float*)d_in[19];
    const float* t_ln2g = (const float*)d_in[20];
    const float* t_ln2b = (const float*)d_in[21];
    const float* dec_w1 = (const float*)d_in[22];
    const float* dec_b1 = (const float*)d_in[23];
    const float* dec_w2 = (const float*)d_in[24];
    const float* dec_b2 = (const float*)d_in[25];
    const float* st_sw1 = (const float*)d_in[26];
    const float* st_sb1 = (const float*)d_in[27];
    const float* st_sw2 = (const float*)d_in[28];
    const float* st_sb2 = (const float*)d_in[29];
    const float* st_dw  = (const float*)d_in[30];
    const float* st_db  = (const float*)d_in[31];
    const float* st_cw  = (const float*)d_in[32];
    const float* st_cb  = (const float*)d_in[33];
    float* out = (float*)d_out;

    // ---- workspace carve ----
    char* ws = (char*)d_ws;
    size_t off = 0;
    auto alloc = [&](size_t bytes) -> void* {
        void* p = ws + off;
        off += (bytes + 255) & ~(size_t)255;
        return p;
    };
    int*   knn   = (int*)  alloc((size_t)B_ * N_ * KG_ * 4);
    float* G     = (float*)alloc((size_t)B_ * N_ * N_ * 4);
    float* agg   = (float*)alloc((size_t)B_ * N_ * 64 * 4);
    float* x64   = (float*)alloc((size_t)B_ * N_ * 64 * 4);
    float* xb    = (float*)alloc((size_t)B_ * N_ * D_ * 4);
    float* x     = (float*)alloc((size_t)B_ * N_ * D_ * 4);
    float* q     = (float*)alloc((size_t)B_ * N_ * D_ * 4);
    float* k     = (float*)alloc((size_t)B_ * N_ * D_ * 4);
    float* v     = (float*)alloc((size_t)B_ * N_ * D_ * 4);
    float* attnb = (float*)alloc((size_t)B_ * N_ * D_ * 4);
    float* ffh   = (float*)alloc((size_t)B_ * N_ * 512 * 4);
    float* ffo   = (float*)alloc((size_t)B_ * N_ * D_ * 4);
    float* gc    = (float*)alloc((size_t)B_ * D_ * 4);
    float* dech  = (float*)alloc((size_t)B_ * D_ * 4);
    float* pts0  = (float*)alloc((size_t)B_ * COARSE_ * 3 * 4);
    float* pts1  = (float*)alloc((size_t)B_ * 1024 * 3 * 4);
    float* pts2  = (float*)alloc((size_t)B_ * 2048 * 3 * 4);
    float* comb  = (float*)alloc((size_t)B_ * 2048 * 6 * 4);
    float* seedh = (float*)alloc((size_t)B_ * 2048 * 128 * 4);
    float* seed  = (float*)alloc((size_t)B_ * 2048 * 128 * 4);
    float* hb    = (float*)alloc((size_t)B_ * 2048 * 256 * 4);

    const int rows = B_ * N_;   // 2048

    // ---- graph encoder ----
    knn_self_kernel<<<B_, N_, 0, stream>>>(coords, knn);
    gram_kernel<<<cdiv(B_ * N_ * N_, 256), 256, 0, stream>>>(coords, G);
    gcn_agg_kernel<<<cdiv(rows * 3, 256), 256, 0, stream>>>(coords, knn, agg, 3);
    linear_kernel<true><<<cdiv(rows * 64, 256), 256, 0, stream>>>(agg, gcn_w0, gcn_b0, x64, rows, 3, 64);
    gcn_agg_kernel<<<cdiv(rows * 64, 256), 256, 0, stream>>>(x64, knn, agg, 64);
    linear_kernel<true><<<cdiv(rows * 128, 256), 256, 0, stream>>>(agg, gcn_w1, gcn_b1, xb, rows, 64, 128);
    linear_kernel<false><<<cdiv(rows * 128, 256), 256, 0, stream>>>(xb, enc_fw, enc_fb, x, rows, 128, 128);

    // ---- transformer ----
    for (int i = 0; i < L_; ++i) {
        linear_kernel<false><<<cdiv(rows * 128, 256), 256, 0, stream>>>(x, t_wq + i * 16384, t_bq + i * 128, q, rows, 128, 128);
        linear_kernel<false><<<cdiv(rows * 128, 256), 256, 0, stream>>>(x, t_wk + i * 16384, t_bk + i * 128, k, rows, 128, 128);
        linear_kernel<false><<<cdiv(rows * 128, 256), 256, 0, stream>>>(x, t_wv + i * 16384, t_bv + i * 128, v, rows, 128, 128);
        attn_kernel<<<(B_ * H_ * N_) / 4, 256, 0, stream>>>(q, k, v, G, t_alpha, i, attnb);
        add_ln_kernel<<<rows / 4, 256, 0, stream>>>(attnb, x, t_ln1g + i * 128, t_ln1b + i * 128, x);
        linear_kernel<true><<<cdiv(rows * 512, 256), 256, 0, stream>>>(x, t_f1w + i * 128 * 512, t_f1b + i * 512, ffh, rows, 128, 512);
        linear_kernel<false><<<cdiv(rows * 128, 256), 256, 0, stream>>>(ffh, t_f2w + i * 512 * 128, t_f2b + i * 128, ffo, rows, 512, 128);
        add_ln_kernel<<<rows / 4, 256, 0, stream>>>(ffo, x, t_ln2g + i * 128, t_ln2b + i * 128, x);
    }

    // ---- decoder coarse ----
    colmean_kernel<<<B_, D_, 0, stream>>>(x, gc);
    linear_kernel<true><<<cdiv(B_ * 128, 256), 256, 0, stream>>>(gc, dec_w1, dec_b1, dech, B_, 128, 128);
    linear_kernel<false><<<cdiv(B_ * 1536, 256), 256, 0, stream>>>(dech, dec_w2, dec_b2, pts0, B_, 128, 1536);

    // ---- refine stages ----
    const float* pred = pts0;
    float* outs[3] = { pts1, pts2, out };
    int Nq = COARSE_;
    for (int s = 0; s < 3; ++s) {
        neigh_comb_kernel<<<dim3(cdiv(Nq, 256), B_), 256, 0, stream>>>(coords, pred, comb, Nq);
        int srows = B_ * Nq;
        linear_kernel<true><<<cdiv(srows * 128, 256), 256, 0, stream>>>(comb, st_sw1 + s * 6 * 128, st_sb1 + s * 128, seedh, srows, 6, 128);
        linear_kernel<false><<<cdiv(srows * 128, 256), 256, 0, stream>>>(seedh, st_sw2 + s * 128 * 128, st_sb2 + s * 128, seed, srows, 128, 128);
        convt_kernel<<<cdiv(srows * 256, 256), 256, 0, stream>>>(seed, st_dw + s * 128 * 256, st_db + s * 128, hb, srows);
        child_kernel<<<cdiv(srows * 6, 256), 256, 0, stream>>>(hb, st_cw + s * 3 * 128, st_cb + s * 3, pred, outs[s], Nq);
        pred = outs[s];
        Nq <<= 1;
    }
}

// Round 2
// 3399.110 us; speedup vs baseline: 1.7292x; 1.7292x over previous
//
#include <hip/hip_runtime.h>

// ---------------------------------------------------------------------------
// FullModelSnowflake: KNN -> GCN x2 -> enc -> 4x transformer (geom bias attn)
// -> decoder -> 3x local-refine stages.  B=2, N=1024, D=128, H=8, DK=16.
// R1: fix knn occupancy + scratch-spilled insert; rewrite attention as
// thread-per-query with uniform (broadcast) K/V loads and on-the-fly G bias.
// ---------------------------------------------------------------------------

#define B_ 2
#define N_ 1024
#define D_ 128
#define H_ 8
#define DK_ 16
#define L_ 4
#define KG_ 16
#define KLOC_ 8
#define COARSE_ 512

static __device__ __forceinline__ float wave_sum(float v) {
    #pragma unroll
    for (int off = 32; off > 0; off >>= 1) v += __shfl_xor(v, off);
    return v;
}

// ---------------- KNN self graph (k=16, exclude self) ----------------------
// grid: B*16 blocks x 64 threads.  coords + r^2 staged in LDS per block.
__global__ void knn_self_kernel(const float* __restrict__ coords,
                                int* __restrict__ knn) {
    int blk = blockIdx.x;
    int b = blk >> 4;
    int n = (blk & 15) * 64 + threadIdx.x;
    __shared__ float cx[N_], cy[N_], cz[N_], r2[N_];
    const float* cb = coords + (size_t)b * N_ * 3;
    for (int i = threadIdx.x; i < N_; i += 64) {
        float x = cb[i * 3], y = cb[i * 3 + 1], z = cb[i * 3 + 2];
        cx[i] = x; cy[i] = y; cz[i] = z;
        r2[i] = x * x + y * y + z * z;
    }
    __syncthreads();
    float qx = cx[n], qy = cy[n], qz = cz[n], q2 = r2[n];
    float bd[KG_]; int bi[KG_];
    #pragma unroll
    for (int j = 0; j < KG_; ++j) { bd[j] = 3e38f; bi[j] = 0; }
    for (int m = 0; m < N_; ++m) {
        float dot = qx * cx[m] + qy * cy[m] + qz * cz[m];
        float d = (q2 - 2.0f * dot) + r2[m];
        d = (m == n) ? 3e38f : d;
        if (d < bd[KG_ - 1]) {
            // static-index insert network: stays in registers, no scratch
            #pragma unroll
            for (int j = KG_ - 1; j > 0; --j) {
                bool shf = d < bd[j - 1];
                bool plc = !shf && (d < bd[j]);
                float nbv = shf ? bd[j - 1] : (plc ? d : bd[j]);
                int   niv = shf ? bi[j - 1] : (plc ? m : bi[j]);
                bd[j] = nbv; bi[j] = niv;
            }
            if (d < bd[0]) { bd[0] = d; bi[0] = m; }
        }
    }
    int* o = knn + ((size_t)b * N_ + n) * KG_;
    #pragma unroll
    for (int j = 0; j < KG_; ++j) o[j] = bi[j];
}

// ---------------- GCN aggregation: (x + sum_nb) / (k+1) --------------------
__global__ void gcn_agg_kernel(const float* __restrict__ x,
                               const int* __restrict__ knn,
                               float* __restrict__ agg, int C) {
    int i = blockIdx.x * blockDim.x + threadIdx.x;
    if (i >= B_ * N_ * C) return;
    int c = i % C;
    int n = (i / C) % N_;
    int b = i / (C * N_);
    const int* id = knn + ((size_t)b * N_ + n) * KG_;
    float s = x[((size_t)b * N_ + n) * C + c];
    #pragma unroll
    for (int j = 0; j < KG_; ++j) s += x[((size_t)b * N_ + id[j]) * C + c];
    agg[i] = s * (1.0f / (KG_ + 1));
}

// ---------------- generic linear: Y = act(X @ W + b) -----------------------
template <bool RELU>
__global__ void linear_kernel(const float* __restrict__ X,
                              const float* __restrict__ W,
                              const float* __restrict__ bias,
                              float* __restrict__ Y,
                              int rows, int Cin, int Cout) {
    int idx = blockIdx.x * blockDim.x + threadIdx.x;
    if (idx >= rows * Cout) return;
    int r = idx / Cout, o = idx - r * Cout;
    const float* x = X + (size_t)r * Cin;
    float acc = bias[o];
    for (int c = 0; c < Cin; ++c) acc += x[c] * W[(size_t)c * Cout + o];
    if (RELU) acc = fmaxf(acc, 0.f);
    Y[idx] = acc;
}

// ---------------- fused attention v2: thread per (b,h,n) -------------------
// Block covers one (b,h) and 64 consecutive n: K/V/coords loads in the m-loop
// are wave-uniform (single L1 line broadcast).  G bias computed on the fly.
__global__ void attn_kernel(const float* __restrict__ q,
                            const float* __restrict__ k,
                            const float* __restrict__ v,
                            const float* __restrict__ coords,
                            const float* __restrict__ alphap, int layer,
                            float* __restrict__ outp) {
    int blk = blockIdx.x;              // b*128 + h*16 + nb
    int lane = threadIdx.x;
    int nb = blk & 15;
    int h = (blk >> 4) & 7;
    int b = blk >> 7;
    int n = nb * 64 + lane;
    float alpha = alphap[layer];
    const float* qp = q + ((size_t)(b * N_ + n) * D_ + h * DK_);
    float qv[DK_];
    #pragma unroll
    for (int d = 0; d < DK_; ++d) qv[d] = qp[d];
    const float* cb = coords + (size_t)b * N_ * 3;
    float cnx = cb[n * 3], cny = cb[n * 3 + 1], cnz = cb[n * 3 + 2];
    const float* kb = k + (size_t)b * N_ * D_ + h * DK_;
    const float* vb = v + (size_t)b * N_ * D_ + h * DK_;
    float mx = -3e38f, sum = 0.f;
    float acc[DK_];
    #pragma unroll
    for (int d = 0; d < DK_; ++d) acc[d] = 0.f;
    for (int c = 0; c < N_ / 16; ++c) {
        float s[16];
        float cm = -3e38f;
        #pragma unroll
        for (int j = 0; j < 16; ++j) {
            int m = c * 16 + j;
            const float4* kr = (const float4*)(kb + (size_t)m * D_);
            float4 k0 = kr[0], k1 = kr[1], k2 = kr[2], k3 = kr[3];
            float dot = qv[0] * k0.x + qv[1] * k0.y + qv[2] * k0.z + qv[3] * k0.w
                      + qv[4] * k1.x + qv[5] * k1.y + qv[6] * k1.z + qv[7] * k1.w
                      + qv[8] * k2.x + qv[9] * k2.y + qv[10] * k2.z + qv[11] * k2.w
                      + qv[12] * k3.x + qv[13] * k3.y + qv[14] * k3.z + qv[15] * k3.w;
            float gx = cb[m * 3] * cnx + cb[m * 3 + 1] * cny + cb[m * 3 + 2] * cnz;
            s[j] = dot * 0.25f + alpha * gx;
            cm = fmaxf(cm, s[j]);
        }
        float nm = fmaxf(mx, cm);
        float sc = __expf(mx - nm);
        sum *= sc;
        #pragma unroll
        for (int d = 0; d < DK_; ++d) acc[d] *= sc;
        mx = nm;
        #pragma unroll
        for (int j = 0; j < 16; ++j) {
            int m = c * 16 + j;
            float p = __expf(s[j] - mx);
            sum += p;
            const float4* vr = (const float4*)(vb + (size_t)m * D_);
            float4 v0 = vr[0], v1 = vr[1], v2 = vr[2], v3 = vr[3];
            acc[0] += p * v0.x;  acc[1] += p * v0.y;  acc[2] += p * v0.z;  acc[3] += p * v0.w;
            acc[4] += p * v1.x;  acc[5] += p * v1.y;  acc[6] += p * v1.z;  acc[7] += p * v1.w;
            acc[8] += p * v2.x;  acc[9] += p * v2.y;  acc[10] += p * v2.z; acc[11] += p * v2.w;
            acc[12] += p * v3.x; acc[13] += p * v3.y; acc[14] += p * v3.z; acc[15] += p * v3.w;
        }
    }
    float inv = 1.0f / sum;
    float* op = outp + ((size_t)(b * N_ + n) * D_ + h * DK_);
    #pragma unroll
    for (int d = 0; d < DK_; ++d) op[d] = acc[d] * inv;
}

// ---------------- residual add + LayerNorm (row=128), 1 wave/row -----------
__global__ void add_ln_kernel(const float* __restrict__ a,
                              const float* __restrict__ res,
                              const float* __restrict__ g,
                              const float* __restrict__ bt,
                              float* __restrict__ outp) {
    int row = blockIdx.x * 4 + (threadIdx.x >> 6);
    int lane = threadIdx.x & 63;
    const float* ar = a + (size_t)row * D_;
    const float* rr = res + (size_t)row * D_;
    float v0 = ar[lane] + rr[lane];
    float v1 = ar[lane + 64] + rr[lane + 64];
    float mean = wave_sum(v0 + v1) * (1.0f / D_);
    float d0 = v0 - mean, d1 = v1 - mean;
    float var = wave_sum(d0 * d0 + d1 * d1) * (1.0f / D_);
    float rstd = rsqrtf(var + 1e-5f);
    float* orow = outp + (size_t)row * D_;
    orow[lane] = d0 * rstd * g[lane] + bt[lane];
    orow[lane + 64] = d1 * rstd * g[lane + 64] + bt[lane + 64];
}

// ---------------- column mean over N (global feature) ----------------------
// grid: B blocks x 512 threads (4 n-slices x 128 dims)
__global__ void colmean_kernel(const float* __restrict__ x,
                               float* __restrict__ gc) {
    int b = blockIdx.x;
    int d = threadIdx.x & 127;
    int sl = threadIdx.x >> 7;
    __shared__ float part[4][128];
    float s = 0.f;
    const float* xb = x + (size_t)b * N_ * D_;
    for (int n = sl * 256; n < sl * 256 + 256; ++n) s += xb[(size_t)n * D_ + d];
    part[sl][d] = s;
    __syncthreads();
    if (sl == 0)
        gc[b * D_ + d] = (part[0][d] + part[1][d] + part[2][d] + part[3][d]) * (1.0f / N_);
}

// ---------------- local KNN (k=8) mean + build comb=[pred,nm] --------------
// grid: (Nq/64, B) x 64 threads
__global__ void neigh_comb_kernel(const float* __restrict__ part,
                                  const float* __restrict__ pred,
                                  float* __restrict__ comb, int Nq) {
    int b = blockIdx.y;
    int n = blockIdx.x * 64 + threadIdx.x;
    __shared__ float cx[N_], cy[N_], cz[N_], r2[N_];
    const float* pb = part + (size_t)b * N_ * 3;
    for (int i = threadIdx.x; i < N_; i += 64) {
        float x = pb[i * 3], y = pb[i * 3 + 1], z = pb[i * 3 + 2];
        cx[i] = x; cy[i] = y; cz[i] = z;
        r2[i] = x * x + y * y + z * z;
    }
    __syncthreads();
    const float* pr = pred + ((size_t)b * Nq + n) * 3;
    float qx = pr[0], qy = pr[1], qz = pr[2];
    float q2 = qx * qx + qy * qy + qz * qz;
    float bd[KLOC_]; int bi[KLOC_];
    #pragma unroll
    for (int j = 0; j < KLOC_; ++j) { bd[j] = 3e38f; bi[j] = 0; }
    for (int m = 0; m < N_; ++m) {
        float dot = qx * cx[m] + qy * cy[m] + qz * cz[m];
        float d = (q2 - 2.0f * dot) + r2[m];
        if (d < bd[KLOC_ - 1]) {
            #pragma unroll
            for (int j = KLOC_ - 1; j > 0; --j) {
                bool shf = d < bd[j - 1];
                bool plc = !shf && (d < bd[j]);
                float nbv = shf ? bd[j - 1] : (plc ? d : bd[j]);
                int   niv = shf ? bi[j - 1] : (plc ? m : bi[j]);
                bd[j] = nbv; bi[j] = niv;
            }
            if (d < bd[0]) { bd[0] = d; bi[0] = m; }
        }
    }
    float sx = 0.f, sy = 0.f, sz = 0.f;
    #pragma unroll
    for (int j = 0; j < KLOC_; ++j) { sx += cx[bi[j]]; sy += cy[bi[j]]; sz += cz[bi[j]]; }
    float* o = comb + ((size_t)b * Nq + n) * 6;
    o[0] = qx; o[1] = qy; o[2] = qz;
    o[3] = sx * (1.0f / KLOC_); o[4] = sy * (1.0f / KLOC_); o[5] = sz * (1.0f / KLOC_);
}

// ---------------- ConvT1d(k=2,s=2) on len-1 seq ----------------------------
__global__ void convt_kernel(const float* __restrict__ seed,
                             const float* __restrict__ dw,
                             const float* __restrict__ db,
                             float* __restrict__ h, int rows) {
    int idx = blockIdx.x * blockDim.x + threadIdx.x;
    if (idx >= rows * 256) return;
    int r = idx >> 8, ot = idx & 255;
    const float* x = seed + (size_t)r * 128;
    float acc = db[ot >> 1];
    for (int c = 0; c < 128; ++c) acc += x[c] * dw[(size_t)c * 256 + ot];
    h[idx] = fmaxf(acc, 0.f);
}

// ---------------- child = pred + (h . cw + cb), interleaved x2 -------------
__global__ void child_kernel(const float* __restrict__ h,
                             const float* __restrict__ cw,
                             const float* __restrict__ cb,
                             const float* __restrict__ pred,
                             float* __restrict__ outp, int Nq) {
    int idx = blockIdx.x * blockDim.x + threadIdx.x;
    if (idx >= B_ * Nq * 6) return;
    int p = idx % 3;
    int t = (idx / 3) & 1;
    int n = (idx / 6) % Nq;
    int b = idx / (6 * Nq);
    const float* hr = h + ((size_t)b * Nq + n) * 256;
    float acc = cb[p];
    for (int o = 0; o < 128; ++o) acc += hr[o * 2 + t] * cw[p * 128 + o];
    outp[idx] = pred[((size_t)b * Nq + n) * 3 + p] + acc;
}

// ---------------------------------------------------------------------------
static inline int cdiv(int a, int b) { return (a + b - 1) / b; }

extern "C" void kernel_launch(void* const* d_in, const int* in_sizes, int n_in,
                              void* d_out, int out_size, void* d_ws, size_t ws_size,
                              hipStream_t stream) {
    (void)in_sizes; (void)n_in; (void)out_size; (void)ws_size;
    const float* coords = (const float*)d_in[0];
    const float* gcn_w0 = (const float*)d_in[1];
    const float* gcn_b0 = (const float*)d_in[2];
    const float* gcn_w1 = (const float*)d_in[3];
    const float* gcn_b1 = (const float*)d_in[4];
    const float* enc_fw = (const float*)d_in[5];
    const float* enc_fb = (const float*)d_in[6];
    const float* t_wq   = (const float*)d_in[7];
    const float* t_bq   = (const float*)d_in[8];
    const float* t_wk   = (const float*)d_in[9];
    const float* t_bk   = (const float*)d_in[10];
    const float* t_wv   = (const float*)d_in[11];
    const float* t_bv   = (const float*)d_in[12];
    const float* t_alpha= (const float*)d_in[13];
    const float* t_f1w  = (const float*)d_in[14];
    const float* t_f1b  = (const float*)d_in[15];
    const float* t_f2w  = (const float*)d_in[16];
    const float* t_f2b  = (const float*)d_in[17];
    const float* t_ln1g = (const float*)d_in[18];
    const float* t_ln1b = (const float*)d_in[19];
    const float* t_ln2g = (const float*)d_in[20];
    const float* t_ln2b = (const float*)d_in[21];
    const float* dec_w1 = (const float*)d_in[22];
    const float* dec_b1 = (const float*)d_in[23];
    const float* dec_w2 = (const float*)d_in[24];
    const float* dec_b2 = (const float*)d_in[25];
    const float* st_sw1 = (const float*)d_in[26];
    const float* st_sb1 = (const float*)d_in[27];
    const float* st_sw2 = (const float*)d_in[28];
    const float* st_sb2 = (const float*)d_in[29];
    const float* st_dw  = (const float*)d_in[30];
    const float* st_db  = (const float*)d_in[31];
    const float* st_cw  = (const float*)d_in[32];
    const float* st_cb  = (const float*)d_in[33];
    float* out = (float*)d_out;

    // ---- workspace carve ----
    char* ws = (char*)d_ws;
    size_t off = 0;
    auto alloc = [&](size_t bytes) -> void* {
        void* p = ws + off;
        off += (bytes + 255) & ~(size_t)255;
        return p;
    };
    int*   knn   = (int*)  alloc((size_t)B_ * N_ * KG_ * 4);
    float* agg   = (float*)alloc((size_t)B_ * N_ * 64 * 4);
    float* x64   = (float*)alloc((size_t)B_ * N_ * 64 * 4);
    float* xb    = (float*)alloc((size_t)B_ * N_ * D_ * 4);
    float* x     = (float*)alloc((size_t)B_ * N_ * D_ * 4);
    float* q     = (float*)alloc((size_t)B_ * N_ * D_ * 4);
    float* k     = (float*)alloc((size_t)B_ * N_ * D_ * 4);
    float* v     = (float*)alloc((size_t)B_ * N_ * D_ * 4);
    float* attnb = (float*)alloc((size_t)B_ * N_ * D_ * 4);
    float* ffh   = (float*)alloc((size_t)B_ * N_ * 512 * 4);
    float* ffo   = (float*)alloc((size_t)B_ * N_ * D_ * 4);
    float* gc    = (float*)alloc((size_t)B_ * D_ * 4);
    float* dech  = (float*)alloc((size_t)B_ * D_ * 4);
    float* pts0  = (float*)alloc((size_t)B_ * COARSE_ * 3 * 4);
    float* pts1  = (float*)alloc((size_t)B_ * 1024 * 3 * 4);
    float* pts2  = (float*)alloc((size_t)B_ * 2048 * 3 * 4);
    float* comb  = (float*)alloc((size_t)B_ * 2048 * 6 * 4);
    float* seedh = (float*)alloc((size_t)B_ * 2048 * 128 * 4);
    float* seed  = (float*)alloc((size_t)B_ * 2048 * 128 * 4);
    float* hb    = (float*)alloc((size_t)B_ * 2048 * 256 * 4);

    const int rows = B_ * N_;   // 2048

    // ---- graph encoder ----
    knn_self_kernel<<<B_ * 16, 64, 0, stream>>>(coords, knn);
    gcn_agg_kernel<<<cdiv(rows * 3, 256), 256, 0, stream>>>(coords, knn, agg, 3);
    linear_kernel<true><<<cdiv(rows * 64, 256), 256, 0, stream>>>(agg, gcn_w0, gcn_b0, x64, rows, 3, 64);
    gcn_agg_kernel<<<cdiv(rows * 64, 256), 256, 0, stream>>>(x64, knn, agg, 64);
    linear_kernel<true><<<cdiv(rows * 128, 256), 256, 0, stream>>>(agg, gcn_w1, gcn_b1, xb, rows, 64, 128);
    linear_kernel<false><<<cdiv(rows * 128, 256), 256, 0, stream>>>(xb, enc_fw, enc_fb, x, rows, 128, 128);

    // ---- transformer ----
    for (int i = 0; i < L_; ++i) {
        linear_kernel<false><<<cdiv(rows * 128, 256), 256, 0, stream>>>(x, t_wq + i * 16384, t_bq + i * 128, q, rows, 128, 128);
        linear_kernel<false><<<cdiv(rows * 128, 256), 256, 0, stream>>>(x, t_wk + i * 16384, t_bk + i * 128, k, rows, 128, 128);
        linear_kernel<false><<<cdiv(rows * 128, 256), 256, 0, stream>>>(x, t_wv + i * 16384, t_bv + i * 128, v, rows, 128, 128);
        attn_kernel<<<B_ * H_ * (N_ / 64), 64, 0, stream>>>(q, k, v, coords, t_alpha, i, attnb);
        add_ln_kernel<<<rows / 4, 256, 0, stream>>>(attnb, x, t_ln1g + i * 128, t_ln1b + i * 128, x);
        linear_kernel<true><<<cdiv(rows * 512, 256), 256, 0, stream>>>(x, t_f1w + i * 128 * 512, t_f1b + i * 512, ffh, rows, 128, 512);
        linear_kernel<false><<<cdiv(rows * 128, 256), 256, 0, stream>>>(ffh, t_f2w + i * 512 * 128, t_f2b + i * 128, ffo, rows, 512, 128);
        add_ln_kernel<<<rows / 4, 256, 0, stream>>>(ffo, x, t_ln2g + i * 128, t_ln2b + i * 128, x);
    }

    // ---- decoder coarse ----
    colmean_kernel<<<B_, 512, 0, stream>>>(x, gc);
    linear_kernel<true><<<cdiv(B_ * 128, 256), 256, 0, stream>>>(gc, dec_w1, dec_b1, dech, B_, 128, 128);
    linear_kernel<false><<<cdiv(B_ * 1536, 256), 256, 0, stream>>>(dech, dec_w2, dec_b2, pts0, B_, 128, 1536);

    // ---- refine stages ----
    const float* pred = pts0;
    float* outs[3] = { pts1, pts2, out };
    int Nq = COARSE_;
    for (int s = 0; s < 3; ++s) {
        neigh_comb_kernel<<<dim3(Nq / 64, B_), 64, 0, stream>>>(coords, pred, comb, Nq);
        int srows = B_ * Nq;
        linear_kernel<true><<<cdiv(srows * 128, 256), 256, 0, stream>>>(comb, st_sw1 + s * 6 * 128, st_sb1 + s * 128, seedh, srows, 6, 128);
        linear_kernel<false><<<cdiv(srows * 128, 256), 256, 0, stream>>>(seedh, st_sw2 + s * 128 * 128, st_sb2 + s * 128, seed, srows, 128, 128);
        convt_kernel<<<cdiv(srows * 256, 256), 256, 0, stream>>>(seed, st_dw + s * 128 * 256, st_db + s * 128, hb, srows);
        child_kernel<<<cdiv(srows * 6, 256), 256, 0, stream>>>(hb, st_cw + s * 3 * 128, st_cb + s * 3, pred, outs[s], Nq);
        pred = outs[s];
        Nq <<= 1;
    }
}

// Round 3
// 2832.140 us; speedup vs baseline: 2.0753x; 1.2002x over previous
//
#include <hip/hip_runtime.h>

// ---------------------------------------------------------------------------
// FullModelSnowflake.  R2: two-pass KNN (chunked partial top-k + merge) to fix
// the 0.3%-occupancy latency-bound KNN kernels; float4-wide linear kernels.
// ---------------------------------------------------------------------------

#define B_ 2
#define N_ 1024
#define D_ 128
#define H_ 8
#define DK_ 16
#define L_ 4
#define KG_ 16
#define KLOC_ 8
#define COARSE_ 512
#define NCH_ 16          // candidate chunks (64 candidates each)

static __device__ __forceinline__ float wave_sum(float v) {
    #pragma unroll
    for (int off = 32; off > 0; off >>= 1) v += __shfl_xor(v, off);
    return v;
}

// ---------------- KNN pass 1: per-chunk partial top-16 ---------------------
// block = 1 wave = 64 queries x 1 chunk of 64 candidates.
// blockIdx.x = b*256 + ch*16 + qb
__global__ void knn_part_kernel(const float* __restrict__ coords,
                                float* __restrict__ pd, int* __restrict__ pi) {
    int blk = blockIdx.x;
    int qb = blk & 15;
    int ch = (blk >> 4) & 15;
    int b = blk >> 8;
    int lane = threadIdx.x;
    int q = qb * 64 + lane;
    __shared__ float4 sc[64];
    const float* cb = coords + (size_t)b * N_ * 3;
    {
        int m = ch * 64 + lane;
        float x = cb[m * 3], y = cb[m * 3 + 1], z = cb[m * 3 + 2];
        sc[lane] = make_float4(x, y, z, x * x + y * y + z * z);
    }
    __syncthreads();
    float qx = cb[q * 3], qy = cb[q * 3 + 1], qz = cb[q * 3 + 2];
    float q2 = qx * qx + qy * qy + qz * qz;
    float bd[KG_]; int bi[KG_];
    #pragma unroll
    for (int j = 0; j < KG_; ++j) { bd[j] = 3e38f; bi[j] = 0; }
    for (int j = 0; j < 64; ++j) {
        int m = ch * 64 + j;
        float4 c = sc[j];
        float dot = qx * c.x + qy * c.y + qz * c.z;
        float d = (q2 - 2.0f * dot) + c.w;
        d = (m == q) ? 3e38f : d;
        if (d < bd[KG_ - 1]) {
            #pragma unroll
            for (int jj = KG_ - 1; jj > 0; --jj) {
                bool shf = d < bd[jj - 1];
                bool plc = !shf && (d < bd[jj]);
                bd[jj] = shf ? bd[jj - 1] : (plc ? d : bd[jj]);
                bi[jj] = shf ? bi[jj - 1] : (plc ? m : bi[jj]);
            }
            if (d < bd[0]) { bd[0] = d; bi[0] = m; }
        }
    }
    size_t base = (((size_t)b * N_ + q) * NCH_ + ch) * KG_;
    #pragma unroll
    for (int j = 0; j < KG_; ++j) { pd[base + j] = bd[j]; pi[base + j] = bi[j]; }
}

// ---------------- KNN pass 2: merge 16 sorted lists ------------------------
__global__ void knn_merge_kernel(const float* __restrict__ pd,
                                 const int* __restrict__ pi,
                                 int* __restrict__ knn) {
    int blk = blockIdx.x;
    int b = blk >> 4;
    int q = (blk & 15) * 64 + threadIdx.x;
    float bd[KG_]; int bi[KG_];
    #pragma unroll
    for (int j = 0; j < KG_; ++j) { bd[j] = 3e38f; bi[j] = 0; }
    size_t base = ((size_t)b * N_ + q) * NCH_ * KG_;
    for (int ch = 0; ch < NCH_; ++ch) {
        const float* cd = pd + base + ch * KG_;
        const int* ci = pi + base + ch * KG_;
        for (int e = 0; e < KG_; ++e) {
            float d = cd[e];
            if (d >= bd[KG_ - 1]) break;   // sorted chunk: rest also fails
            int m = ci[e];
            #pragma unroll
            for (int jj = KG_ - 1; jj > 0; --jj) {
                bool shf = d < bd[jj - 1];
                bool plc = !shf && (d < bd[jj]);
                bd[jj] = shf ? bd[jj - 1] : (plc ? d : bd[jj]);
                bi[jj] = shf ? bi[jj - 1] : (plc ? m : bi[jj]);
            }
            if (d < bd[0]) { bd[0] = d; bi[0] = m; }
        }
    }
    int* o = knn + ((size_t)b * N_ + q) * KG_;
    #pragma unroll
    for (int j = 0; j < KG_; ++j) o[j] = bi[j];
}

// ---------------- local KNN pass 1 (k=8) -----------------------------------
// grid: (Nq/64, NCH, B) x 64
__global__ void loc_part_kernel(const float* __restrict__ part,
                                const float* __restrict__ pred,
                                float* __restrict__ pd, int* __restrict__ pi,
                                int Nq) {
    int qb = blockIdx.x, ch = blockIdx.y, b = blockIdx.z;
    int lane = threadIdx.x;
    int q = qb * 64 + lane;
    __shared__ float4 sc[64];
    const float* pb = part + (size_t)b * N_ * 3;
    {
        int m = ch * 64 + lane;
        float x = pb[m * 3], y = pb[m * 3 + 1], z = pb[m * 3 + 2];
        sc[lane] = make_float4(x, y, z, x * x + y * y + z * z);
    }
    __syncthreads();
    const float* pr = pred + ((size_t)b * Nq + q) * 3;
    float qx = pr[0], qy = pr[1], qz = pr[2];
    float q2 = qx * qx + qy * qy + qz * qz;
    float bd[KLOC_]; int bi[KLOC_];
    #pragma unroll
    for (int j = 0; j < KLOC_; ++j) { bd[j] = 3e38f; bi[j] = 0; }
    for (int j = 0; j < 64; ++j) {
        float4 c = sc[j];
        float dot = qx * c.x + qy * c.y + qz * c.z;
        float d = (q2 - 2.0f * dot) + c.w;
        if (d < bd[KLOC_ - 1]) {
            int m = ch * 64 + j;
            #pragma unroll
            for (int jj = KLOC_ - 1; jj > 0; --jj) {
                bool shf = d < bd[jj - 1];
                bool plc = !shf && (d < bd[jj]);
                bd[jj] = shf ? bd[jj - 1] : (plc ? d : bd[jj]);
                bi[jj] = shf ? bi[jj - 1] : (plc ? m : bi[jj]);
            }
            if (d < bd[0]) { bd[0] = d; bi[0] = m; }
        }
    }
    size_t base = (((size_t)b * Nq + q) * NCH_ + ch) * KLOC_;
    #pragma unroll
    for (int j = 0; j < KLOC_; ++j) { pd[base + j] = bd[j]; pi[base + j] = bi[j]; }
}

// ---------------- local KNN pass 2: merge + neighbor mean + comb -----------
// grid: (Nq/64, B) x 64
__global__ void loc_merge_kernel(const float* __restrict__ part,
                                 const float* __restrict__ pred,
                                 const float* __restrict__ pd,
                                 const int* __restrict__ pi,
                                 float* __restrict__ comb, int Nq) {
    int b = blockIdx.y;
    int q = blockIdx.x * 64 + threadIdx.x;
    float bd[KLOC_]; int bi[KLOC_];
    #pragma unroll
    for (int j = 0; j < KLOC_; ++j) { bd[j] = 3e38f; bi[j] = 0; }
    size_t base = ((size_t)b * Nq + q) * NCH_ * KLOC_;
    for (int ch = 0; ch < NCH_; ++ch) {
        const float* cd = pd + base + ch * KLOC_;
        const int* ci = pi + base + ch * KLOC_;
        for (int e = 0; e < KLOC_; ++e) {
            float d = cd[e];
            if (d >= bd[KLOC_ - 1]) break;
            int m = ci[e];
            #pragma unroll
            for (int jj = KLOC_ - 1; jj > 0; --jj) {
                bool shf = d < bd[jj - 1];
                bool plc = !shf && (d < bd[jj]);
                bd[jj] = shf ? bd[jj - 1] : (plc ? d : bd[jj]);
                bi[jj] = shf ? bi[jj - 1] : (plc ? m : bi[jj]);
            }
            if (d < bd[0]) { bd[0] = d; bi[0] = m; }
        }
    }
    const float* pb = part + (size_t)b * N_ * 3;
    float sx = 0.f, sy = 0.f, sz = 0.f;
    #pragma unroll
    for (int j = 0; j < KLOC_; ++j) {
        int m = bi[j];
        sx += pb[m * 3]; sy += pb[m * 3 + 1]; sz += pb[m * 3 + 2];
    }
    const float* pr = pred + ((size_t)b * Nq + q) * 3;
    float* o = comb + ((size_t)b * Nq + q) * 6;
    o[0] = pr[0]; o[1] = pr[1]; o[2] = pr[2];
    o[3] = sx * (1.0f / KLOC_); o[4] = sy * (1.0f / KLOC_); o[5] = sz * (1.0f / KLOC_);
}

// ---------------- GCN aggregation: (x + sum_nb) / (k+1) --------------------
__global__ void gcn_agg_kernel(const float* __restrict__ x,
                               const int* __restrict__ knn,
                               float* __restrict__ agg, int C) {
    int i = blockIdx.x * blockDim.x + threadIdx.x;
    if (i >= B_ * N_ * C) return;
    int c = i % C;
    int n = (i / C) % N_;
    int b = i / (C * N_);
    const int* id = knn + ((size_t)b * N_ + n) * KG_;
    float s = x[((size_t)b * N_ + n) * C + c];
    #pragma unroll
    for (int j = 0; j < KG_; ++j) s += x[((size_t)b * N_ + id[j]) * C + c];
    agg[i] = s * (1.0f / (KG_ + 1));
}

// ---------------- linear v2: 4 outputs per thread --------------------------
template <bool RELU>
__global__ void linear4_kernel(const float* __restrict__ X,
                               const float* __restrict__ W,
                               const float* __restrict__ bias,
                               float* __restrict__ Y,
                               int rows, int Cin, int Cout) {
    int co4 = Cout >> 2;
    int idx = blockIdx.x * blockDim.x + threadIdx.x;
    if (idx >= rows * co4) return;
    int r = idx / co4, o4 = (idx - r * co4) << 2;
    const float* x = X + (size_t)r * Cin;
    float4 acc = *(const float4*)(bias + o4);
    for (int c = 0; c < Cin; ++c) {
        float xv = x[c];
        float4 w = *(const float4*)(W + (size_t)c * Cout + o4);
        acc.x += xv * w.x; acc.y += xv * w.y; acc.z += xv * w.z; acc.w += xv * w.w;
    }
    if (RELU) {
        acc.x = fmaxf(acc.x, 0.f); acc.y = fmaxf(acc.y, 0.f);
        acc.z = fmaxf(acc.z, 0.f); acc.w = fmaxf(acc.w, 0.f);
    }
    *(float4*)(Y + (size_t)r * Cout + o4) = acc;
}

// ---------------- fused attention: thread per (b,h,n) ----------------------
__global__ void attn_kernel(const float* __restrict__ q,
                            const float* __restrict__ k,
                            const float* __restrict__ v,
                            const float* __restrict__ coords,
                            const float* __restrict__ alphap, int layer,
                            float* __restrict__ outp) {
    int blk = blockIdx.x;              // b*128 + h*16 + nb
    int lane = threadIdx.x;
    int nb = blk & 15;
    int h = (blk >> 4) & 7;
    int b = blk >> 7;
    int n = nb * 64 + lane;
    float alpha = alphap[layer];
    const float* qp = q + ((size_t)(b * N_ + n) * D_ + h * DK_);
    float qv[DK_];
    #pragma unroll
    for (int d = 0; d < DK_; ++d) qv[d] = qp[d];
    const float* cb = coords + (size_t)b * N_ * 3;
    float cnx = cb[n * 3], cny = cb[n * 3 + 1], cnz = cb[n * 3 + 2];
    const float* kb = k + (size_t)b * N_ * D_ + h * DK_;
    const float* vb = v + (size_t)b * N_ * D_ + h * DK_;
    float mx = -3e38f, sum = 0.f;
    float acc[DK_];
    #pragma unroll
    for (int d = 0; d < DK_; ++d) acc[d] = 0.f;
    for (int c = 0; c < N_ / 16; ++c) {
        float s[16];
        float cm = -3e38f;
        #pragma unroll
        for (int j = 0; j < 16; ++j) {
            int m = c * 16 + j;
            const float4* kr = (const float4*)(kb + (size_t)m * D_);
            float4 k0 = kr[0], k1 = kr[1], k2 = kr[2], k3 = kr[3];
            float dot = qv[0] * k0.x + qv[1] * k0.y + qv[2] * k0.z + qv[3] * k0.w
                      + qv[4] * k1.x + qv[5] * k1.y + qv[6] * k1.z + qv[7] * k1.w
                      + qv[8] * k2.x + qv[9] * k2.y + qv[10] * k2.z + qv[11] * k2.w
                      + qv[12] * k3.x + qv[13] * k3.y + qv[14] * k3.z + qv[15] * k3.w;
            float gx = cb[m * 3] * cnx + cb[m * 3 + 1] * cny + cb[m * 3 + 2] * cnz;
            s[j] = dot * 0.25f + alpha * gx;
            cm = fmaxf(cm, s[j]);
        }
        float nm = fmaxf(mx, cm);
        float sc = __expf(mx - nm);
        sum *= sc;
        #pragma unroll
        for (int d = 0; d < DK_; ++d) acc[d] *= sc;
        mx = nm;
        #pragma unroll
        for (int j = 0; j < 16; ++j) {
            int m = c * 16 + j;
            float p = __expf(s[j] - mx);
            sum += p;
            const float4* vr = (const float4*)(vb + (size_t)m * D_);
            float4 v0 = vr[0], v1 = vr[1], v2 = vr[2], v3 = vr[3];
            acc[0] += p * v0.x;  acc[1] += p * v0.y;  acc[2] += p * v0.z;  acc[3] += p * v0.w;
            acc[4] += p * v1.x;  acc[5] += p * v1.y;  acc[6] += p * v1.z;  acc[7] += p * v1.w;
            acc[8] += p * v2.x;  acc[9] += p * v2.y;  acc[10] += p * v2.z; acc[11] += p * v2.w;
            acc[12] += p * v3.x; acc[13] += p * v3.y; acc[14] += p * v3.z; acc[15] += p * v3.w;
        }
    }
    float inv = 1.0f / sum;
    float* op = outp + ((size_t)(b * N_ + n) * D_ + h * DK_);
    #pragma unroll
    for (int d = 0; d < DK_; ++d) op[d] = acc[d] * inv;
}

// ---------------- residual add + LayerNorm (row=128), 1 wave/row -----------
__global__ void add_ln_kernel(const float* __restrict__ a,
                              const float* __restrict__ res,
                              const float* __restrict__ g,
                              const float* __restrict__ bt,
                              float* __restrict__ outp) {
    int row = blockIdx.x * 4 + (threadIdx.x >> 6);
    int lane = threadIdx.x & 63;
    const float* ar = a + (size_t)row * D_;
    const float* rr = res + (size_t)row * D_;
    float v0 = ar[lane] + rr[lane];
    float v1 = ar[lane + 64] + rr[lane + 64];
    float mean = wave_sum(v0 + v1) * (1.0f / D_);
    float d0 = v0 - mean, d1 = v1 - mean;
    float var = wave_sum(d0 * d0 + d1 * d1) * (1.0f / D_);
    float rstd = rsqrtf(var + 1e-5f);
    float* orow = outp + (size_t)row * D_;
    orow[lane] = d0 * rstd * g[lane] + bt[lane];
    orow[lane + 64] = d1 * rstd * g[lane + 64] + bt[lane + 64];
}

// ---------------- column mean over N (global feature) ----------------------
__global__ void colmean_kernel(const float* __restrict__ x,
                               float* __restrict__ gc) {
    int b = blockIdx.x;
    int d = threadIdx.x & 127;
    int sl = threadIdx.x >> 7;
    __shared__ float part[4][128];
    float s = 0.f;
    const float* xb = x + (size_t)b * N_ * D_;
    for (int n = sl * 256; n < sl * 256 + 256; ++n) s += xb[(size_t)n * D_ + d];
    part[sl][d] = s;
    __syncthreads();
    if (sl == 0)
        gc[b * D_ + d] = (part[0][d] + part[1][d] + part[2][d] + part[3][d]) * (1.0f / N_);
}

// ---------------- ConvT1d(k=2,s=2): 4 outputs per thread -------------------
__global__ void convt_kernel(const float* __restrict__ seed,
                             const float* __restrict__ dw,
                             const float* __restrict__ db,
                             float* __restrict__ h, int rows) {
    int idx = blockIdx.x * blockDim.x + threadIdx.x;   // rows * 64
    if (idx >= rows * 64) return;
    int r = idx >> 6, o4 = (idx & 63) << 2;
    const float* x = seed + (size_t)r * 128;
    float4 acc = make_float4(db[o4 >> 1], db[o4 >> 1], db[(o4 >> 1) + 1], db[(o4 >> 1) + 1]);
    for (int c = 0; c < 128; ++c) {
        float xv = x[c];
        float4 w = *(const float4*)(dw + (size_t)c * 256 + o4);
        acc.x += xv * w.x; acc.y += xv * w.y; acc.z += xv * w.z; acc.w += xv * w.w;
    }
    acc.x = fmaxf(acc.x, 0.f); acc.y = fmaxf(acc.y, 0.f);
    acc.z = fmaxf(acc.z, 0.f); acc.w = fmaxf(acc.w, 0.f);
    *(float4*)(h + (size_t)r * 256 + o4) = acc;
}

// ---------------- child = pred + (h . cw + cb), interleaved x2 -------------
__global__ void child_kernel(const float* __restrict__ h,
                             const float* __restrict__ cw,
                             const float* __restrict__ cb,
                             const float* __restrict__ pred,
                             float* __restrict__ outp, int Nq) {
    int idx = blockIdx.x * blockDim.x + threadIdx.x;
    if (idx >= B_ * Nq * 6) return;
    int p = idx % 3;
    int t = (idx / 3) & 1;
    int n = (idx / 6) % Nq;
    int b = idx / (6 * Nq);
    const float* hr = h + ((size_t)b * Nq + n) * 256;
    float acc = cb[p];
    for (int o = 0; o < 128; ++o) acc += hr[o * 2 + t] * cw[p * 128 + o];
    outp[idx] = pred[((size_t)b * Nq + n) * 3 + p] + acc;
}

// ---------------------------------------------------------------------------
static inline int cdiv(int a, int b) { return (a + b - 1) / b; }

extern "C" void kernel_launch(void* const* d_in, const int* in_sizes, int n_in,
                              void* d_out, int out_size, void* d_ws, size_t ws_size,
                              hipStream_t stream) {
    (void)in_sizes; (void)n_in; (void)out_size; (void)ws_size;
    const float* coords = (const float*)d_in[0];
    const float* gcn_w0 = (const float*)d_in[1];
    const float* gcn_b0 = (const float*)d_in[2];
    const float* gcn_w1 = (const float*)d_in[3];
    const float* gcn_b1 = (const float*)d_in[4];
    const float* enc_fw = (const float*)d_in[5];
    const float* enc_fb = (const float*)d_in[6];
    const float* t_wq   = (const float*)d_in[7];
    const float* t_bq   = (const float*)d_in[8];
    const float* t_wk   = (const float*)d_in[9];
    const float* t_bk   = (const float*)d_in[10];
    const float* t_wv   = (const float*)d_in[11];
    const float* t_bv   = (const float*)d_in[12];
    const float* t_alpha= (const float*)d_in[13];
    const float* t_f1w  = (const float*)d_in[14];
    const float* t_f1b  = (const float*)d_in[15];
    const float* t_f2w  = (const float*)d_in[16];
    const float* t_f2b  = (const float*)d_in[17];
    const float* t_ln1g = (const float*)d_in[18];
    const float* t_ln1b = (const float*)d_in[19];
    const float* t_ln2g = (const float*)d_in[20];
    const float* t_ln2b = (const float*)d_in[21];
    const float* dec_w1 = (const float*)d_in[22];
    const float* dec_b1 = (const float*)d_in[23];
    const float* dec_w2 = (const float*)d_in[24];
    const float* dec_b2 = (const float*)d_in[25];
    const float* st_sw1 = (const float*)d_in[26];
    const float* st_sb1 = (const float*)d_in[27];
    const float* st_sw2 = (const float*)d_in[28];
    const float* st_sb2 = (const float*)d_in[29];
    const float* st_dw  = (const float*)d_in[30];
    const float* st_db  = (const float*)d_in[31];
    const float* st_cw  = (const float*)d_in[32];
    const float* st_cb  = (const float*)d_in[33];
    float* out = (float*)d_out;

    // ---- workspace carve ----
    char* ws = (char*)d_ws;
    size_t off = 0;
    auto alloc = [&](size_t bytes) -> void* {
        void* p = ws + off;
        off += (bytes + 255) & ~(size_t)255;
        return p;
    };
    int*   knn   = (int*)  alloc((size_t)B_ * N_ * KG_ * 4);
    float* ppd   = (float*)alloc((size_t)B_ * 2048 * NCH_ * KG_ * 4);  // shared partial dists
    int*   ppi   = (int*)  alloc((size_t)B_ * 2048 * NCH_ * KG_ * 4);  // shared partial idx
    float* agg   = (float*)alloc((size_t)B_ * N_ * 64 * 4);
    float* x64   = (float*)alloc((size_t)B_ * N_ * 64 * 4);
    float* xb    = (float*)alloc((size_t)B_ * N_ * D_ * 4);
    float* x     = (float*)alloc((size_t)B_ * N_ * D_ * 4);
    float* q     = (float*)alloc((size_t)B_ * N_ * D_ * 4);
    float* k     = (float*)alloc((size_t)B_ * N_ * D_ * 4);
    float* v     = (float*)alloc((size_t)B_ * N_ * D_ * 4);
    float* attnb = (float*)alloc((size_t)B_ * N_ * D_ * 4);
    float* ffh   = (float*)alloc((size_t)B_ * N_ * 512 * 4);
    float* ffo   = (float*)alloc((size_t)B_ * N_ * D_ * 4);
    float* gc    = (float*)alloc((size_t)B_ * D_ * 4);
    float* dech  = (float*)alloc((size_t)B_ * D_ * 4);
    float* pts0  = (float*)alloc((size_t)B_ * COARSE_ * 3 * 4);
    float* pts1  = (float*)alloc((size_t)B_ * 1024 * 3 * 4);
    float* pts2  = (float*)alloc((size_t)B_ * 2048 * 3 * 4);
    float* comb  = (float*)alloc((size_t)B_ * 2048 * 6 * 4);
    float* seedh = (float*)alloc((size_t)B_ * 2048 * 128 * 4);
    float* seed  = (float*)alloc((size_t)B_ * 2048 * 128 * 4);
    float* hb    = (float*)alloc((size_t)B_ * 2048 * 256 * 4);

    const int rows = B_ * N_;   // 2048

    // ---- graph encoder ----
    knn_part_kernel<<<B_ * NCH_ * 16, 64, 0, stream>>>(coords, ppd, ppi);
    knn_merge_kernel<<<B_ * 16, 64, 0, stream>>>(ppd, ppi, knn);
    gcn_agg_kernel<<<cdiv(rows * 3, 256), 256, 0, stream>>>(coords, knn, agg, 3);
    linear4_kernel<true><<<cdiv(rows * 16, 256), 256, 0, stream>>>(agg, gcn_w0, gcn_b0, x64, rows, 3, 64);
    gcn_agg_kernel<<<cdiv(rows * 64, 256), 256, 0, stream>>>(x64, knn, agg, 64);
    linear4_kernel<true><<<cdiv(rows * 32, 256), 256, 0, stream>>>(agg, gcn_w1, gcn_b1, xb, rows, 64, 128);
    linear4_kernel<false><<<cdiv(rows * 32, 256), 256, 0, stream>>>(xb, enc_fw, enc_fb, x, rows, 128, 128);

    // ---- transformer ----
    for (int i = 0; i < L_; ++i) {
        linear4_kernel<false><<<cdiv(rows * 32, 256), 256, 0, stream>>>(x, t_wq + i * 16384, t_bq + i * 128, q, rows, 128, 128);
        linear4_kernel<false><<<cdiv(rows * 32, 256), 256, 0, stream>>>(x, t_wk + i * 16384, t_bk + i * 128, k, rows, 128, 128);
        linear4_kernel<false><<<cdiv(rows * 32, 256), 256, 0, stream>>>(x, t_wv + i * 16384, t_bv + i * 128, v, rows, 128, 128);
        attn_kernel<<<B_ * H_ * (N_ / 64), 64, 0, stream>>>(q, k, v, coords, t_alpha, i, attnb);
        add_ln_kernel<<<rows / 4, 256, 0, stream>>>(attnb, x, t_ln1g + i * 128, t_ln1b + i * 128, x);
        linear4_kernel<true><<<cdiv(rows * 128, 256), 256, 0, stream>>>(x, t_f1w + i * 128 * 512, t_f1b + i * 512, ffh, rows, 128, 512);
        linear4_kernel<false><<<cdiv(rows * 32, 256), 256, 0, stream>>>(ffh, t_f2w + i * 512 * 128, t_f2b + i * 128, ffo, rows, 512, 128);
        add_ln_kernel<<<rows / 4, 256, 0, stream>>>(ffo, x, t_ln2g + i * 128, t_ln2b + i * 128, x);
    }

    // ---- decoder coarse ----
    colmean_kernel<<<B_, 512, 0, stream>>>(x, gc);
    linear4_kernel<true><<<cdiv(B_ * 32, 256), 256, 0, stream>>>(gc, dec_w1, dec_b1, dech, B_, 128, 128);
    linear4_kernel<false><<<cdiv(B_ * 384, 256), 256, 0, stream>>>(dech, dec_w2, dec_b2, pts0, B_, 128, 1536);

    // ---- refine stages ----
    const float* pred = pts0;
    float* outs[3] = { pts1, pts2, out };
    int Nq = COARSE_;
    for (int s = 0; s < 3; ++s) {
        loc_part_kernel<<<dim3(Nq / 64, NCH_, B_), 64, 0, stream>>>(coords, pred, ppd, ppi, Nq);
        loc_merge_kernel<<<dim3(Nq / 64, B_), 64, 0, stream>>>(coords, pred, ppd, ppi, comb, Nq);
        int srows = B_ * Nq;
        linear4_kernel<true><<<cdiv(srows * 32, 256), 256, 0, stream>>>(comb, st_sw1 + s * 6 * 128, st_sb1 + s * 128, seedh, srows, 6, 128);
        linear4_kernel<false><<<cdiv(srows * 32, 256), 256, 0, stream>>>(seedh, st_sw2 + s * 128 * 128, st_sb2 + s * 128, seed, srows, 128, 128);
        convt_kernel<<<cdiv(srows * 64, 256), 256, 0, stream>>>(seed, st_dw + s * 128 * 256, st_db + s * 128, hb, srows);
        child_kernel<<<cdiv(srows * 6, 256), 256, 0, stream>>>(hb, st_cw + s * 3 * 128, st_cb + s * 3, pred, outs[s], Nq);
        pred = outs[s];
        Nq <<= 1;
    }
}

// Round 4
// 1168.681 us; speedup vs baseline: 5.0292x; 2.4234x over previous
//
#include <hip/hip_runtime.h>

// ---------------------------------------------------------------------------
// FullModelSnowflake.  R3: split-K attention (8 waves/block + LDS merge) with
// XCD-aware block mapping so all query-blocks of one (b,h) share an XCD L2.
// ---------------------------------------------------------------------------

#define B_ 2
#define N_ 1024
#define D_ 128
#define H_ 8
#define DK_ 16
#define L_ 4
#define KG_ 16
#define KLOC_ 8
#define COARSE_ 512
#define NCH_ 16          // candidate chunks (64 candidates each)
#define AW_ 8            // waves per attention block

static __device__ __forceinline__ float wave_sum(float v) {
    #pragma unroll
    for (int off = 32; off > 0; off >>= 1) v += __shfl_xor(v, off);
    return v;
}

// ---------------- KNN pass 1: per-chunk partial top-16 ---------------------
__global__ void knn_part_kernel(const float* __restrict__ coords,
                                float* __restrict__ pd, int* __restrict__ pi) {
    int blk = blockIdx.x;
    int qb = blk & 15;
    int ch = (blk >> 4) & 15;
    int b = blk >> 8;
    int lane = threadIdx.x;
    int q = qb * 64 + lane;
    __shared__ float4 sc[64];
    const float* cb = coords + (size_t)b * N_ * 3;
    {
        int m = ch * 64 + lane;
        float x = cb[m * 3], y = cb[m * 3 + 1], z = cb[m * 3 + 2];
        sc[lane] = make_float4(x, y, z, x * x + y * y + z * z);
    }
    __syncthreads();
    float qx = cb[q * 3], qy = cb[q * 3 + 1], qz = cb[q * 3 + 2];
    float q2 = qx * qx + qy * qy + qz * qz;
    float bd[KG_]; int bi[KG_];
    #pragma unroll
    for (int j = 0; j < KG_; ++j) { bd[j] = 3e38f; bi[j] = 0; }
    for (int j = 0; j < 64; ++j) {
        int m = ch * 64 + j;
        float4 c = sc[j];
        float dot = qx * c.x + qy * c.y + qz * c.z;
        float d = (q2 - 2.0f * dot) + c.w;
        d = (m == q) ? 3e38f : d;
        if (d < bd[KG_ - 1]) {
            #pragma unroll
            for (int jj = KG_ - 1; jj > 0; --jj) {
                bool shf = d < bd[jj - 1];
                bool plc = !shf && (d < bd[jj]);
                bd[jj] = shf ? bd[jj - 1] : (plc ? d : bd[jj]);
                bi[jj] = shf ? bi[jj - 1] : (plc ? m : bi[jj]);
            }
            if (d < bd[0]) { bd[0] = d; bi[0] = m; }
        }
    }
    size_t base = (((size_t)b * N_ + q) * NCH_ + ch) * KG_;
    #pragma unroll
    for (int j = 0; j < KG_; ++j) { pd[base + j] = bd[j]; pi[base + j] = bi[j]; }
}

// ---------------- KNN pass 2: merge 16 sorted lists ------------------------
__global__ void knn_merge_kernel(const float* __restrict__ pd,
                                 const int* __restrict__ pi,
                                 int* __restrict__ knn) {
    int blk = blockIdx.x;
    int b = blk >> 4;
    int q = (blk & 15) * 64 + threadIdx.x;
    float bd[KG_]; int bi[KG_];
    #pragma unroll
    for (int j = 0; j < KG_; ++j) { bd[j] = 3e38f; bi[j] = 0; }
    size_t base = ((size_t)b * N_ + q) * NCH_ * KG_;
    for (int ch = 0; ch < NCH_; ++ch) {
        const float* cd = pd + base + ch * KG_;
        const int* ci = pi + base + ch * KG_;
        for (int e = 0; e < KG_; ++e) {
            float d = cd[e];
            if (d >= bd[KG_ - 1]) break;   // sorted chunk: rest also fails
            int m = ci[e];
            #pragma unroll
            for (int jj = KG_ - 1; jj > 0; --jj) {
                bool shf = d < bd[jj - 1];
                bool plc = !shf && (d < bd[jj]);
                bd[jj] = shf ? bd[jj - 1] : (plc ? d : bd[jj]);
                bi[jj] = shf ? bi[jj - 1] : (plc ? m : bi[jj]);
            }
            if (d < bd[0]) { bd[0] = d; bi[0] = m; }
        }
    }
    int* o = knn + ((size_t)b * N_ + q) * KG_;
    #pragma unroll
    for (int j = 0; j < KG_; ++j) o[j] = bi[j];
}

// ---------------- local KNN pass 1 (k=8) -----------------------------------
__global__ void loc_part_kernel(const float* __restrict__ part,
                                const float* __restrict__ pred,
                                float* __restrict__ pd, int* __restrict__ pi,
                                int Nq) {
    int qb = blockIdx.x, ch = blockIdx.y, b = blockIdx.z;
    int lane = threadIdx.x;
    int q = qb * 64 + lane;
    __shared__ float4 sc[64];
    const float* pb = part + (size_t)b * N_ * 3;
    {
        int m = ch * 64 + lane;
        float x = pb[m * 3], y = pb[m * 3 + 1], z = pb[m * 3 + 2];
        sc[lane] = make_float4(x, y, z, x * x + y * y + z * z);
    }
    __syncthreads();
    const float* pr = pred + ((size_t)b * Nq + q) * 3;
    float qx = pr[0], qy = pr[1], qz = pr[2];
    float q2 = qx * qx + qy * qy + qz * qz;
    float bd[KLOC_]; int bi[KLOC_];
    #pragma unroll
    for (int j = 0; j < KLOC_; ++j) { bd[j] = 3e38f; bi[j] = 0; }
    for (int j = 0; j < 64; ++j) {
        float4 c = sc[j];
        float dot = qx * c.x + qy * c.y + qz * c.z;
        float d = (q2 - 2.0f * dot) + c.w;
        if (d < bd[KLOC_ - 1]) {
            int m = ch * 64 + j;
            #pragma unroll
            for (int jj = KLOC_ - 1; jj > 0; --jj) {
                bool shf = d < bd[jj - 1];
                bool plc = !shf && (d < bd[jj]);
                bd[jj] = shf ? bd[jj - 1] : (plc ? d : bd[jj]);
                bi[jj] = shf ? bi[jj - 1] : (plc ? m : bi[jj]);
            }
            if (d < bd[0]) { bd[0] = d; bi[0] = m; }
        }
    }
    size_t base = (((size_t)b * Nq + q) * NCH_ + ch) * KLOC_;
    #pragma unroll
    for (int j = 0; j < KLOC_; ++j) { pd[base + j] = bd[j]; pi[base + j] = bi[j]; }
}

// ---------------- local KNN pass 2: merge + neighbor mean + comb -----------
__global__ void loc_merge_kernel(const float* __restrict__ part,
                                 const float* __restrict__ pred,
                                 const float* __restrict__ pd,
                                 const int* __restrict__ pi,
                                 float* __restrict__ comb, int Nq) {
    int b = blockIdx.y;
    int q = blockIdx.x * 64 + threadIdx.x;
    float bd[KLOC_]; int bi[KLOC_];
    #pragma unroll
    for (int j = 0; j < KLOC_; ++j) { bd[j] = 3e38f; bi[j] = 0; }
    size_t base = ((size_t)b * Nq + q) * NCH_ * KLOC_;
    for (int ch = 0; ch < NCH_; ++ch) {
        const float* cd = pd + base + ch * KLOC_;
        const int* ci = pi + base + ch * KLOC_;
        for (int e = 0; e < KLOC_; ++e) {
            float d = cd[e];
            if (d >= bd[KLOC_ - 1]) break;
            int m = ci[e];
            #pragma unroll
            for (int jj = KLOC_ - 1; jj > 0; --jj) {
                bool shf = d < bd[jj - 1];
                bool plc = !shf && (d < bd[jj]);
                bd[jj] = shf ? bd[jj - 1] : (plc ? d : bd[jj]);
                bi[jj] = shf ? bi[jj - 1] : (plc ? m : bi[jj]);
            }
            if (d < bd[0]) { bd[0] = d; bi[0] = m; }
        }
    }
    const float* pb = part + (size_t)b * N_ * 3;
    float sx = 0.f, sy = 0.f, sz = 0.f;
    #pragma unroll
    for (int j = 0; j < KLOC_; ++j) {
        int m = bi[j];
        sx += pb[m * 3]; sy += pb[m * 3 + 1]; sz += pb[m * 3 + 2];
    }
    const float* pr = pred + ((size_t)b * Nq + q) * 3;
    float* o = comb + ((size_t)b * Nq + q) * 6;
    o[0] = pr[0]; o[1] = pr[1]; o[2] = pr[2];
    o[3] = sx * (1.0f / KLOC_); o[4] = sy * (1.0f / KLOC_); o[5] = sz * (1.0f / KLOC_);
}

// ---------------- GCN aggregation: (x + sum_nb) / (k+1) --------------------
__global__ void gcn_agg_kernel(const float* __restrict__ x,
                               const int* __restrict__ knn,
                               float* __restrict__ agg, int C) {
    int i = blockIdx.x * blockDim.x + threadIdx.x;
    if (i >= B_ * N_ * C) return;
    int c = i % C;
    int n = (i / C) % N_;
    int b = i / (C * N_);
    const int* id = knn + ((size_t)b * N_ + n) * KG_;
    float s = x[((size_t)b * N_ + n) * C + c];
    #pragma unroll
    for (int j = 0; j < KG_; ++j) s += x[((size_t)b * N_ + id[j]) * C + c];
    agg[i] = s * (1.0f / (KG_ + 1));
}

// ---------------- linear: 4 outputs per thread -----------------------------
template <bool RELU>
__global__ void linear4_kernel(const float* __restrict__ X,
                               const float* __restrict__ W,
                               const float* __restrict__ bias,
                               float* __restrict__ Y,
                               int rows, int Cin, int Cout) {
    int co4 = Cout >> 2;
    int idx = blockIdx.x * blockDim.x + threadIdx.x;
    if (idx >= rows * co4) return;
    int r = idx / co4, o4 = (idx - r * co4) << 2;
    const float* x = X + (size_t)r * Cin;
    float4 acc = *(const float4*)(bias + o4);
    #pragma unroll 4
    for (int c = 0; c < Cin; ++c) {
        float xv = x[c];
        float4 w = *(const float4*)(W + (size_t)c * Cout + o4);
        acc.x += xv * w.x; acc.y += xv * w.y; acc.z += xv * w.z; acc.w += xv * w.w;
    }
    if (RELU) {
        acc.x = fmaxf(acc.x, 0.f); acc.y = fmaxf(acc.y, 0.f);
        acc.z = fmaxf(acc.z, 0.f); acc.w = fmaxf(acc.w, 0.f);
    }
    *(float4*)(Y + (size_t)r * Cout + o4) = acc;
}

// ---------------- attention v3: split-K, 8 waves/block ---------------------
// blockIdx.x = nb*16 + (b*8+h): the 16 nb-blocks of one (b,h) differ by 16
// (== 0 mod 8) so they land on the same XCD -> K/V slice cached in that L2.
// Each wave scans 128 keys (online softmax); partials merged via LDS.
__global__ __launch_bounds__(64 * AW_) void attn_kernel(
        const float* __restrict__ q,
        const float* __restrict__ k,
        const float* __restrict__ v,
        const float* __restrict__ coords,
        const float* __restrict__ alphap, int layer,
        float* __restrict__ outp) {
    int bh = blockIdx.x & 15;          // b*8 + h
    int nb = blockIdx.x >> 4;          // query block
    int h = bh & 7;
    int b = bh >> 3;
    int wid = threadIdx.x >> 6;
    int lane = threadIdx.x & 63;
    int n = nb * 64 + lane;
    float alpha = alphap[layer];
    const float* qp = q + ((size_t)(b * N_ + n) * D_ + h * DK_);
    float qv[DK_];
    #pragma unroll
    for (int d = 0; d < DK_; ++d) qv[d] = qp[d];
    const float* cb = coords + (size_t)b * N_ * 3;
    float cnx = cb[n * 3], cny = cb[n * 3 + 1], cnz = cb[n * 3 + 2];
    const float* kb = k + (size_t)b * N_ * D_ + h * DK_;
    const float* vb = v + (size_t)b * N_ * D_ + h * DK_;
    float mx = -3e38f, sum = 0.f;
    float acc[DK_];
    #pragma unroll
    for (int d = 0; d < DK_; ++d) acc[d] = 0.f;
    // this wave's key range: [wid*128, wid*128+128)
    for (int c = 0; c < 128 / 16; ++c) {
        int m0 = wid * 128 + c * 16;
        float s[16];
        float cm = -3e38f;
        #pragma unroll
        for (int j = 0; j < 16; ++j) {
            int m = m0 + j;
            const float4* kr = (const float4*)(kb + (size_t)m * D_);
            float4 k0 = kr[0], k1 = kr[1], k2 = kr[2], k3 = kr[3];
            float dot = qv[0] * k0.x + qv[1] * k0.y + qv[2] * k0.z + qv[3] * k0.w
                      + qv[4] * k1.x + qv[5] * k1.y + qv[6] * k1.z + qv[7] * k1.w
                      + qv[8] * k2.x + qv[9] * k2.y + qv[10] * k2.z + qv[11] * k2.w
                      + qv[12] * k3.x + qv[13] * k3.y + qv[14] * k3.z + qv[15] * k3.w;
            float gx = cb[m * 3] * cnx + cb[m * 3 + 1] * cny + cb[m * 3 + 2] * cnz;
            s[j] = dot * 0.25f + alpha * gx;
            cm = fmaxf(cm, s[j]);
        }
        float nm = fmaxf(mx, cm);
        float sc = __expf(mx - nm);
        sum *= sc;
        #pragma unroll
        for (int d = 0; d < DK_; ++d) acc[d] *= sc;
        mx = nm;
        #pragma unroll
        for (int j = 0; j < 16; ++j) {
            int m = m0 + j;
            float p = __expf(s[j] - mx);
            sum += p;
            const float4* vr = (const float4*)(vb + (size_t)m * D_);
            float4 v0 = vr[0], v1 = vr[1], v2 = vr[2], v3 = vr[3];
            acc[0] += p * v0.x;  acc[1] += p * v0.y;  acc[2] += p * v0.z;  acc[3] += p * v0.w;
            acc[4] += p * v1.x;  acc[5] += p * v1.y;  acc[6] += p * v1.z;  acc[7] += p * v1.w;
            acc[8] += p * v2.x;  acc[9] += p * v2.y;  acc[10] += p * v2.z; acc[11] += p * v2.w;
            acc[12] += p * v3.x; acc[13] += p * v3.y; acc[14] += p * v3.z; acc[15] += p * v3.w;
        }
    }
    // ---- merge 8 wave-partials via LDS ----
    __shared__ float smx[AW_][64];
    __shared__ float ssum[AW_][64];
    __shared__ float sacc[64][AW_ * DK_ + 1];   // row stride 129: conflict-free
    smx[wid][lane] = mx;
    ssum[wid][lane] = sum;
    #pragma unroll
    for (int d = 0; d < DK_; ++d) sacc[lane][wid * DK_ + d] = acc[d];
    __syncthreads();
    if (wid == 0) {
        float gmx = smx[0][lane];
        #pragma unroll
        for (int w = 1; w < AW_; ++w) gmx = fmaxf(gmx, smx[w][lane]);
        float scale[AW_];
        float gsum = 0.f;
        #pragma unroll
        for (int w = 0; w < AW_; ++w) {
            float sc = __expf(smx[w][lane] - gmx);
            scale[w] = sc;
            gsum += ssum[w][lane] * sc;
        }
        float inv = 1.0f / gsum;
        float* op = outp + ((size_t)(b * N_ + n) * D_ + h * DK_);
        #pragma unroll
        for (int d = 0; d < DK_; ++d) {
            float a = 0.f;
            #pragma unroll
            for (int w = 0; w < AW_; ++w) a += sacc[lane][w * DK_ + d] * scale[w];
            op[d] = a * inv;
        }
    }
}

// ---------------- residual add + LayerNorm (row=128), 1 wave/row -----------
__global__ void add_ln_kernel(const float* __restrict__ a,
                              const float* __restrict__ res,
                              const float* __restrict__ g,
                              const float* __restrict__ bt,
                              float* __restrict__ outp) {
    int row = blockIdx.x * 4 + (threadIdx.x >> 6);
    int lane = threadIdx.x & 63;
    const float* ar = a + (size_t)row * D_;
    const float* rr = res + (size_t)row * D_;
    float v0 = ar[lane] + rr[lane];
    float v1 = ar[lane + 64] + rr[lane + 64];
    float mean = wave_sum(v0 + v1) * (1.0f / D_);
    float d0 = v0 - mean, d1 = v1 - mean;
    float var = wave_sum(d0 * d0 + d1 * d1) * (1.0f / D_);
    float rstd = rsqrtf(var + 1e-5f);
    float* orow = outp + (size_t)row * D_;
    orow[lane] = d0 * rstd * g[lane] + bt[lane];
    orow[lane + 64] = d1 * rstd * g[lane + 64] + bt[lane + 64];
}

// ---------------- column mean over N (global feature) ----------------------
__global__ void colmean_kernel(const float* __restrict__ x,
                               float* __restrict__ gc) {
    int b = blockIdx.x;
    int d = threadIdx.x & 127;
    int sl = threadIdx.x >> 7;
    __shared__ float part[4][128];
    float s = 0.f;
    const float* xb = x + (size_t)b * N_ * D_;
    for (int n = sl * 256; n < sl * 256 + 256; ++n) s += xb[(size_t)n * D_ + d];
    part[sl][d] = s;
    __syncthreads();
    if (sl == 0)
        gc[b * D_ + d] = (part[0][d] + part[1][d] + part[2][d] + part[3][d]) * (1.0f / N_);
}

// ---------------- ConvT1d(k=2,s=2): 4 outputs per thread -------------------
__global__ void convt_kernel(const float* __restrict__ seed,
                             const float* __restrict__ dw,
                             const float* __restrict__ db,
                             float* __restrict__ h, int rows) {
    int idx = blockIdx.x * blockDim.x + threadIdx.x;   // rows * 64
    if (idx >= rows * 64) return;
    int r = idx >> 6, o4 = (idx & 63) << 2;
    const float* x = seed + (size_t)r * 128;
    float4 acc = make_float4(db[o4 >> 1], db[o4 >> 1], db[(o4 >> 1) + 1], db[(o4 >> 1) + 1]);
    #pragma unroll 4
    for (int c = 0; c < 128; ++c) {
        float xv = x[c];
        float4 w = *(const float4*)(dw + (size_t)c * 256 + o4);
        acc.x += xv * w.x; acc.y += xv * w.y; acc.z += xv * w.z; acc.w += xv * w.w;
    }
    acc.x = fmaxf(acc.x, 0.f); acc.y = fmaxf(acc.y, 0.f);
    acc.z = fmaxf(acc.z, 0.f); acc.w = fmaxf(acc.w, 0.f);
    *(float4*)(h + (size_t)r * 256 + o4) = acc;
}

// ---------------- child = pred + (h . cw + cb), interleaved x2 -------------
__global__ void child_kernel(const float* __restrict__ h,
                             const float* __restrict__ cw,
                             const float* __restrict__ cb,
                             const float* __restrict__ pred,
                             float* __restrict__ outp, int Nq) {
    int idx = blockIdx.x * blockDim.x + threadIdx.x;
    if (idx >= B_ * Nq * 6) return;
    int p = idx % 3;
    int t = (idx / 3) & 1;
    int n = (idx / 6) % Nq;
    int b = idx / (6 * Nq);
    const float* hr = h + ((size_t)b * Nq + n) * 256;
    float acc = cb[p];
    #pragma unroll 4
    for (int o = 0; o < 128; ++o) acc += hr[o * 2 + t] * cw[p * 128 + o];
    outp[idx] = pred[((size_t)b * Nq + n) * 3 + p] + acc;
}

// ---------------------------------------------------------------------------
static inline int cdiv(int a, int b) { return (a + b - 1) / b; }

extern "C" void kernel_launch(void* const* d_in, const int* in_sizes, int n_in,
                              void* d_out, int out_size, void* d_ws, size_t ws_size,
                              hipStream_t stream) {
    (void)in_sizes; (void)n_in; (void)out_size; (void)ws_size;
    const float* coords = (const float*)d_in[0];
    const float* gcn_w0 = (const float*)d_in[1];
    const float* gcn_b0 = (const float*)d_in[2];
    const float* gcn_w1 = (const float*)d_in[3];
    const float* gcn_b1 = (const float*)d_in[4];
    const float* enc_fw = (const float*)d_in[5];
    const float* enc_fb = (const float*)d_in[6];
    const float* t_wq   = (const float*)d_in[7];
    const float* t_bq   = (const float*)d_in[8];
    const float* t_wk   = (const float*)d_in[9];
    const float* t_bk   = (const float*)d_in[10];
    const float* t_wv   = (const float*)d_in[11];
    const float* t_bv   = (const float*)d_in[12];
    const float* t_alpha= (const float*)d_in[13];
    const float* t_f1w  = (const float*)d_in[14];
    const float* t_f1b  = (const float*)d_in[15];
    const float* t_f2w  = (const float*)d_in[16];
    const float* t_f2b  = (const float*)d_in[17];
    const float* t_ln1g = (const float*)d_in[18];
    const float* t_ln1b = (const float*)d_in[19];
    const float* t_ln2g = (const float*)d_in[20];
    const float* t_ln2b = (const float*)d_in[21];
    const float* dec_w1 = (const float*)d_in[22];
    const float* dec_b1 = (const float*)d_in[23];
    const float* dec_w2 = (const float*)d_in[24];
    const float* dec_b2 = (const float*)d_in[25];
    const float* st_sw1 = (const float*)d_in[26];
    const float* st_sb1 = (const float*)d_in[27];
    const float* st_sw2 = (const float*)d_in[28];
    const float* st_sb2 = (const float*)d_in[29];
    const float* st_dw  = (const float*)d_in[30];
    const float* st_db  = (const float*)d_in[31];
    const float* st_cw  = (const float*)d_in[32];
    const float* st_cb  = (const float*)d_in[33];
    float* out = (float*)d_out;

    // ---- workspace carve ----
    char* ws = (char*)d_ws;
    size_t off = 0;
    auto alloc = [&](size_t bytes) -> void* {
        void* p = ws + off;
        off += (bytes + 255) & ~(size_t)255;
        return p;
    };
    int*   knn   = (int*)  alloc((size_t)B_ * N_ * KG_ * 4);
    float* ppd   = (float*)alloc((size_t)B_ * 2048 * NCH_ * KG_ * 4);
    int*   ppi   = (int*)  alloc((size_t)B_ * 2048 * NCH_ * KG_ * 4);
    float* agg   = (float*)alloc((size_t)B_ * N_ * 64 * 4);
    float* x64   = (float*)alloc((size_t)B_ * N_ * 64 * 4);
    float* xb    = (float*)alloc((size_t)B_ * N_ * D_ * 4);
    float* x     = (float*)alloc((size_t)B_ * N_ * D_ * 4);
    float* q     = (float*)alloc((size_t)B_ * N_ * D_ * 4);
    float* k     = (float*)alloc((size_t)B_ * N_ * D_ * 4);
    float* v     = (float*)alloc((size_t)B_ * N_ * D_ * 4);
    float* attnb = (float*)alloc((size_t)B_ * N_ * D_ * 4);
    float* ffh   = (float*)alloc((size_t)B_ * N_ * 512 * 4);
    float* ffo   = (float*)alloc((size_t)B_ * N_ * D_ * 4);
    float* gc    = (float*)alloc((size_t)B_ * D_ * 4);
    float* dech  = (float*)alloc((size_t)B_ * D_ * 4);
    float* pts0  = (float*)alloc((size_t)B_ * COARSE_ * 3 * 4);
    float* pts1  = (float*)alloc((size_t)B_ * 1024 * 3 * 4);
    float* pts2  = (float*)alloc((size_t)B_ * 2048 * 3 * 4);
    float* comb  = (float*)alloc((size_t)B_ * 2048 * 6 * 4);
    float* seedh = (float*)alloc((size_t)B_ * 2048 * 128 * 4);
    float* seed  = (float*)alloc((size_t)B_ * 2048 * 128 * 4);
    float* hb    = (float*)alloc((size_t)B_ * 2048 * 256 * 4);

    const int rows = B_ * N_;   // 2048

    // ---- graph encoder ----
    knn_part_kernel<<<B_ * NCH_ * 16, 64, 0, stream>>>(coords, ppd, ppi);
    knn_merge_kernel<<<B_ * 16, 64, 0, stream>>>(ppd, ppi, knn);
    gcn_agg_kernel<<<cdiv(rows * 3, 256), 256, 0, stream>>>(coords, knn, agg, 3);
    linear4_kernel<true><<<cdiv(rows * 16, 256), 256, 0, stream>>>(agg, gcn_w0, gcn_b0, x64, rows, 3, 64);
    gcn_agg_kernel<<<cdiv(rows * 64, 256), 256, 0, stream>>>(x64, knn, agg, 64);
    linear4_kernel<true><<<cdiv(rows * 32, 256), 256, 0, stream>>>(agg, gcn_w1, gcn_b1, xb, rows, 64, 128);
    linear4_kernel<false><<<cdiv(rows * 32, 256), 256, 0, stream>>>(xb, enc_fw, enc_fb, x, rows, 128, 128);

    // ---- transformer ----
    for (int i = 0; i < L_; ++i) {
        linear4_kernel<false><<<cdiv(rows * 32, 256), 256, 0, stream>>>(x, t_wq + i * 16384, t_bq + i * 128, q, rows, 128, 128);
        linear4_kernel<false><<<cdiv(rows * 32, 256), 256, 0, stream>>>(x, t_wk + i * 16384, t_bk + i * 128, k, rows, 128, 128);
        linear4_kernel<false><<<cdiv(rows * 32, 256), 256, 0, stream>>>(x, t_wv + i * 16384, t_bv + i * 128, v, rows, 128, 128);
        attn_kernel<<<B_ * H_ * (N_ / 64), 64 * AW_, 0, stream>>>(q, k, v, coords, t_alpha, i, attnb);
        add_ln_kernel<<<rows / 4, 256, 0, stream>>>(attnb, x, t_ln1g + i * 128, t_ln1b + i * 128, x);
        linear4_kernel<true><<<cdiv(rows * 128, 256), 256, 0, stream>>>(x, t_f1w + i * 128 * 512, t_f1b + i * 512, ffh, rows, 128, 512);
        linear4_kernel<false><<<cdiv(rows * 32, 256), 256, 0, stream>>>(ffh, t_f2w + i * 512 * 128, t_f2b + i * 128, ffo, rows, 512, 128);
        add_ln_kernel<<<rows / 4, 256, 0, stream>>>(ffo, x, t_ln2g + i * 128, t_ln2b + i * 128, x);
    }

    // ---- decoder coarse ----
    colmean_kernel<<<B_, 512, 0, stream>>>(x, gc);
    linear4_kernel<true><<<cdiv(B_ * 32, 256), 256, 0, stream>>>(gc, dec_w1, dec_b1, dech, B_, 128, 128);
    linear4_kernel<false><<<cdiv(B_ * 384, 256), 256, 0, stream>>>(dech, dec_w2, dec_b2, pts0, B_, 128, 1536);

    // ---- refine stages ----
    const float* pred = pts0;
    float* outs[3] = { pts1, pts2, out };
    int Nq = COARSE_;
    for (int s = 0; s < 3; ++s) {
        loc_part_kernel<<<dim3(Nq / 64, NCH_, B_), 64, 0, stream>>>(coords, pred, ppd, ppi, Nq);
        loc_merge_kernel<<<dim3(Nq / 64, B_), 64, 0, stream>>>(coords, pred, ppd, ppi, comb, Nq);
        int srows = B_ * Nq;
        linear4_kernel<true><<<cdiv(srows * 32, 256), 256, 0, stream>>>(comb, st_sw1 + s * 6 * 128, st_sb1 + s * 128, seedh, srows, 6, 128);
        linear4_kernel<false><<<cdiv(srows * 32, 256), 256, 0, stream>>>(seedh, st_sw2 + s * 128 * 128, st_sb2 + s * 128, seed, srows, 128, 128);
        convt_kernel<<<cdiv(srows * 64, 256), 256, 0, stream>>>(seed, st_dw + s * 128 * 256, st_db + s * 128, hb, srows);
        child_kernel<<<cdiv(srows * 6, 256), 256, 0, stream>>>(hb, st_cw + s * 3 * 128, st_cb + s * 3, pred, outs[s], Nq);
        pred = outs[s];
        Nq <<= 1;
    }
}